// Round 4
// baseline (2120.285 us; speedup 1.0000x reference)
//
#include <hip/hip_runtime.h>
#include <stdint.h>

using u16 = unsigned short;
using u32 = unsigned int;

typedef __bf16 bf16x8 __attribute__((ext_vector_type(8)));
typedef float f32x4 __attribute__((ext_vector_type(4)));

__device__ __forceinline__ u16 f2bf(float f){
  u32 u = __float_as_uint(f);
  return (u16)((u + 0x7FFFu + ((u >> 16) & 1u)) >> 16);
}
__device__ __forceinline__ float bf2f(u16 h){
  return __uint_as_float(((u32)h) << 16);
}
__device__ __forceinline__ void split2(float x, u16& hi, u16& lo){
  hi = f2bf(x);
  lo = f2bf(x - bf2f(hi));
}
template<int SH>
__device__ __forceinline__ int swz(int off){ return off ^ (((off >> SH) & 7) << 4); }

// ---------------- fp32 -> (hi,lo) bf16 split, one float4 per thread ----------
__global__ __launch_bounds__(256) void k_split(const float* __restrict__ src,
                                               u16* __restrict__ hi,
                                               u16* __restrict__ lo)
{
  int i = blockIdx.x * 256 + threadIdx.x;
  float4 v = ((const float4*)src)[i];
  ushort4 h, l;
  split2(v.x, h.x, l.x);
  split2(v.y, h.y, l.y);
  split2(v.z, h.z, l.z);
  split2(v.w, h.w, l.w);
  ((ushort4*)hi)[i] = h;
  ((ushort4*)lo)[i] = l;
}

// ---------------- bias precompute: bias[h][q][j] = bf16(table[relidx[q][j]][h])
__global__ __launch_bounds__(256) void k_bias(const int* __restrict__ relidx,
                                              const float* __restrict__ table,
                                              u16* __restrict__ bias)
{
  int q = blockIdx.x;
  int j0 = threadIdx.x * 4;
  int4 idx = *(const int4*)(relidx + q * 1024 + j0);
#pragma unroll
  for (int h = 0; h < 12; ++h){
    ushort4 o;
    o.x = f2bf(table[(size_t)idx.x * 12 + h]);
    o.y = f2bf(table[(size_t)idx.y * 12 + h]);
    o.z = f2bf(table[(size_t)idx.z * 12 + h]);
    o.w = f2bf(table[(size_t)idx.w * 12 + h]);
    *(ushort4*)(bias + ((size_t)h << 20) + q * 1024 + j0) = o;
  }
}

// ---------------- 128x128 tile GEMM, K' = 3*768 (split-bf16 3-term) ----------
// EPI 0: QKV. Q/K -> flat [8192][1536] row-major (dense stores);
//        V -> V^T (b,h,d,n) via LDS transpose (dense 256B runs).
// EPI 1: proj (bias, fp32 row-major out).
template<int EPI>
__global__ __launch_bounds__(256) void k_gemm(
    const u16* __restrict__ A0, const u16* __restrict__ A1, const u16* __restrict__ A2,
    const u16* __restrict__ B0, const u16* __restrict__ B1, const u16* __restrict__ B2,
    const float* __restrict__ bq, const float* __restrict__ bv, const float* __restrict__ pb,
    u16* __restrict__ QKhi, u16* __restrict__ QKlo,
    u16* __restrict__ Vthi, u16* __restrict__ Vtlo,
    float* __restrict__ Cout)
{
  __shared__ u16 As[128 * 32];
  __shared__ u16 Bs[128 * 32];
  const int tid = threadIdx.x;
  const int lane = tid & 63;
  const int wid = tid >> 6;
  const int wr = wid >> 1, wc = wid & 1;
  const int g = lane >> 4, cl = lane & 15;
  const int bm = blockIdx.y << 7, bn = blockIdx.x << 7;
  const int rowA = tid >> 2, csA = tid & 3;

  f32x4 acc[4][4];
  f32x4 z4 = {0.f, 0.f, 0.f, 0.f};
#pragma unroll
  for (int i = 0; i < 4; ++i)
#pragma unroll
    for (int j = 0; j < 4; ++j) acc[i][j] = z4;

  float4 ra[2], rb[2];
  auto ldt = [&](int t, float4* xa, float4* xb){
    int ph = t / 24;
    int kin = (t - ph * 24) * 32;
    const u16* Ap = ph == 0 ? A0 : (ph == 1 ? A1 : A2);
    const u16* Bp = ph == 0 ? B0 : (ph == 1 ? B1 : B2);
#pragma unroll
    for (int i = 0; i < 2; ++i){
      xa[i] = *(const float4*)(Ap + (size_t)(bm + rowA + i * 64) * 768 + kin + csA * 8);
      xb[i] = *(const float4*)(Bp + (size_t)(bn + rowA + i * 64) * 768 + kin + csA * 8);
    }
  };
  ldt(0, ra, rb);

  for (int t = 0; t < 72; ++t){
    __syncthreads();
#pragma unroll
    for (int i = 0; i < 2; ++i){
      int s16 = (tid + i * 256) * 16;
      *(float4*)((char*)As + swz<6>(s16)) = ra[i];
      *(float4*)((char*)Bs + swz<6>(s16)) = rb[i];
    }
    __syncthreads();
    if (t + 1 < 72) ldt(t + 1, ra, rb);
    bf16x8 af[4], bfv[4];
#pragma unroll
    for (int mf = 0; mf < 4; ++mf)
      af[mf] = *(const bf16x8*)((char*)As + swz<6>(((wr * 64 + mf * 16 + cl) * 32 + g * 8) * 2));
#pragma unroll
    for (int nf = 0; nf < 4; ++nf)
      bfv[nf] = *(const bf16x8*)((char*)Bs + swz<6>(((wc * 64 + nf * 16 + cl) * 32 + g * 8) * 2));
#pragma unroll
    for (int mf = 0; mf < 4; ++mf)
#pragma unroll
      for (int nf = 0; nf < 4; ++nf)
        acc[mf][nf] = __builtin_amdgcn_mfma_f32_16x16x32_bf16(af[mf], bfv[nf], acc[mf][nf], 0, 0, 0);
  }

  if (EPI == 0){
    const int bb = bm >> 10;          // batch (tile never crosses: 1024 % 128 == 0)
    const int tokb = bm & 1023;
    if (blockIdx.x >= 12){
      // ---- V columns: transpose through LDS, coalesced 16B stores of V^T ----
      const int ccolbase = bn - 1536;
      u16* ShiT = As;                 // [32 cols][128 m] u16, swz<8> on byte offsets
      u16* SloT = Bs;
      for (int c = 0; c < 4; ++c){
        __syncthreads();
        if (wc == (c >> 1)){
#pragma unroll
          for (int nf2 = 0; nf2 < 2; ++nf2){
            int nf = (c & 1) * 2 + nf2;
            int cc = nf2 * 16 + cl;               // 0..31 within chunk
            float bvv = bv[ccolbase + c * 32 + cc];
#pragma unroll
            for (int mf = 0; mf < 4; ++mf){
              ushort4 h4, l4;
              u16 hh_, ll_;
              split2(acc[mf][nf][0] + bvv, hh_, ll_); h4.x = hh_; l4.x = ll_;
              split2(acc[mf][nf][1] + bvv, hh_, ll_); h4.y = hh_; l4.y = ll_;
              split2(acc[mf][nf][2] + bvv, hh_, ll_); h4.z = hh_; l4.z = ll_;
              split2(acc[mf][nf][3] + bvv, hh_, ll_); h4.w = hh_; l4.w = ll_;
              int m0 = wr * 64 + mf * 16 + g * 4;
              int off = cc * 256 + m0 * 2;        // 8B-aligned
              *(ushort4*)((char*)ShiT + swz<8>(off)) = h4;
              *(ushort4*)((char*)SloT + swz<8>(off)) = l4;
            }
          }
        }
        __syncthreads();
#pragma unroll
        for (int i = 0; i < 2; ++i){
          int s = tid + i * 256;
          int dr = s >> 4;                        // 0..31
          int ms = (s & 15) * 8;                  // m start
          int off = dr * 256 + ms * 2;
          int ccol = ccolbase + c * 32 + dr;
          int hh = ccol >> 6, d = ccol & 63;
          size_t gb = ((size_t)(bb * 12 + hh) * 64 + d) * 1024 + tokb + ms;
          *(float4*)(Vthi + gb) = *(const float4*)((char*)ShiT + swz<8>(off));
          *(float4*)(Vtlo + gb) = *(const float4*)((char*)SloT + swz<8>(off));
        }
      }
    } else {
      // ---- Q/K: flat [8192][1536], bias+scale for Q, LDS-staged dense stores
      const bool isQ = (blockIdx.x < 6);
      for (int c = 0; c < 4; ++c){
        __syncthreads();
        if (wr == (c >> 1)){
#pragma unroll
          for (int mi = 0; mi < 2; ++mi){
            int mf = (c & 1) * 2 + mi;
#pragma unroll
            for (int nf = 0; nf < 4; ++nf){
              int col = wc * 64 + nf * 16 + cl;   // 0..127 local
              float bqv = isQ ? bq[bn + col] : 0.f;
#pragma unroll
              for (int r = 0; r < 4; ++r){
                float v = acc[mf][nf][r];
                if (isQ) v = (v + bqv) * 0.125f;
                u16 hi, lo; split2(v, hi, lo);
                int off = ((mi * 16 + g * 4 + r) * 128 + col) * 2;
                *(u16*)((char*)As + swz<6>(off)) = hi;
                *(u16*)((char*)Bs + swz<6>(off)) = lo;
              }
            }
          }
        }
        __syncthreads();
#pragma unroll
        for (int i = 0; i < 2; ++i){
          int s = tid + i * 256;
          int rr = s >> 4;                        // 0..31
          int seg = s & 15;                       // 16B segment across 128 cols
          int off = rr * 256 + seg * 16;
          size_t gb = (size_t)(bm + c * 32 + rr) * 1536 + bn + seg * 8;
          *(float4*)(QKhi + gb) = *(const float4*)((char*)As + swz<6>(off));
          *(float4*)(QKlo + gb) = *(const float4*)((char*)Bs + swz<6>(off));
        }
      }
    }
    return;
  }

  // EPI == 1: proj epilogue, coalesced fp32 stores
#pragma unroll
  for (int mf = 0; mf < 4; ++mf)
#pragma unroll
    for (int nf = 0; nf < 4; ++nf)
#pragma unroll
      for (int r = 0; r < 4; ++r){
        int m = bm + wr * 64 + mf * 16 + g * 4 + r;
        int n = bn + wc * 64 + nf * 16 + cl;
        Cout[(size_t)m * 768 + n] = acc[mf][nf][r] + pb[n];
      }
}

// ---------------- flash attention, split-bf16, precomputed bias --------------
// Q/K from flat [8192][1536] (Q col h*64, K col 768+h*64); V^T (b,h,d,n).
__global__ __launch_bounds__(256) void k_attn(
    const u16* __restrict__ QKhi, const u16* __restrict__ QKlo,
    const u16* __restrict__ Vthi, const u16* __restrict__ Vtlo,
    const u16* __restrict__ bias,
    u16* __restrict__ Ohi, u16* __restrict__ Olo)
{
  __shared__ u16 Ks[64 * 128];   // [j][d_hi | d_lo]   16 KB  (swz<8>)
  __shared__ u16 Vs0[64 * 64];   // [d][j] hi           8 KB  (swz<7>)
  __shared__ u16 Vs1[64 * 64];   // [d][j] lo           8 KB
  __shared__ u16 Ps0[128 * 64];  // [q][j] P hi        16 KB  (swz<7>)
  __shared__ u16 Ps1[128 * 64];  // [q][j] P lo        16 KB

  const int tid = threadIdx.x;
  const int lane = tid & 63;
  const int w = tid >> 6;
  const int g = lane >> 4, cl = lane & 15;
  const int qt = blockIdx.x;
  const int b  = blockIdx.y;
  const int h  = blockIdx.z;
  const size_t rowbase = (size_t)b * 1024;             // token row base
  const size_t bhv = (size_t)(b * 12 + h) * (1024 * 64);
  const u16* bias_w = bias + ((size_t)h << 20) + (size_t)(qt * 128 + w * 32) * 1024;

  // Q fragments live in registers for the whole kernel (A' = [Qhi|Qhi|Qlo])
  bf16x8 aq[2][4];
#pragma unroll
  for (int mf = 0; mf < 2; ++mf){
    const u16* qh = QKhi + (rowbase + qt * 128 + w * 32 + mf * 16 + cl) * 1536 + h * 64;
    const u16* ql = QKlo + (rowbase + qt * 128 + w * 32 + mf * 16 + cl) * 1536 + h * 64;
    aq[mf][0] = *(const bf16x8*)(qh + g * 8);
    aq[mf][1] = *(const bf16x8*)(qh + 32 + g * 8);
    aq[mf][2] = *(const bf16x8*)(ql + g * 8);
    aq[mf][3] = *(const bf16x8*)(ql + 32 + g * 8);
  }

  f32x4 o[2][4];
  float m_run[2][4], l_run[2][4];
  f32x4 z4 = {0.f, 0.f, 0.f, 0.f};
#pragma unroll
  for (int mf = 0; mf < 2; ++mf){
#pragma unroll
    for (int nd = 0; nd < 4; ++nd) o[mf][nd] = z4;
#pragma unroll
    for (int r = 0; r < 4; ++r){ m_run[mf][r] = -1e30f; l_run[mf][r] = 0.f; }
  }

  float4 kv[8];
  auto ldkv = [&](int jt){
#pragma unroll
    for (int i = 0; i < 2; ++i){
      int s = tid + i * 256;
      int row = s >> 3, cs = s & 7;
      size_t kr = (rowbase + jt * 64 + row) * 1536 + 768 + h * 64 + cs * 8;
      kv[i]     = *(const float4*)(QKhi + kr);
      kv[2 + i] = *(const float4*)(QKlo + kr);
      kv[4 + i] = *(const float4*)(Vthi + bhv + (size_t)row * 1024 + jt * 64 + cs * 8);
      kv[6 + i] = *(const float4*)(Vtlo + bhv + (size_t)row * 1024 + jt * 64 + cs * 8);
    }
  };
  ldkv(0);

  const int AI[6] = {0, 1, 0, 1, 2, 3};
  const int BI[6] = {0, 1, 2, 3, 0, 1};

  for (int jt = 0; jt < 16; ++jt){
    __syncthreads();
#pragma unroll
    for (int i = 0; i < 2; ++i){
      int s = tid + i * 256;
      int row = s >> 3, cs = s & 7;
      *(float4*)((char*)Ks  + swz<8>(row * 256 + cs * 16))       = kv[i];
      *(float4*)((char*)Ks  + swz<8>(row * 256 + 128 + cs * 16)) = kv[2 + i];
      *(float4*)((char*)Vs0 + swz<7>(row * 128 + cs * 16))       = kv[4 + i];
      *(float4*)((char*)Vs1 + swz<7>(row * 128 + cs * 16))       = kv[6 + i];
    }
    __syncthreads();
    if (jt < 15) ldkv(jt + 1);

    // -------- S = Q K^T (3-term) --------
    f32x4 s[2][4];
#pragma unroll
    for (int mf = 0; mf < 2; ++mf)
#pragma unroll
      for (int nf = 0; nf < 4; ++nf) s[mf][nf] = z4;
#pragma unroll
    for (int ks = 0; ks < 6; ++ks){
      int t = BI[ks];
      int colb = ((t >> 1) * 64 + (t & 1) * 32 + g * 8) * 2;
      bf16x8 b4[4];
#pragma unroll
      for (int nf = 0; nf < 4; ++nf)
        b4[nf] = *(const bf16x8*)((char*)Ks + swz<8>((nf * 16 + cl) * 256 + colb));
#pragma unroll
      for (int mf = 0; mf < 2; ++mf)
#pragma unroll
        for (int nf = 0; nf < 4; ++nf)
          s[mf][nf] = __builtin_amdgcn_mfma_f32_16x16x32_bf16(aq[mf][AI[ks]], b4[nf], s[mf][nf], 0, 0, 0);
    }

    // -------- precomputed bias + online softmax --------
#pragma unroll
    for (int mf = 0; mf < 2; ++mf){
#pragma unroll
      for (int nf = 0; nf < 4; ++nf){
        int jc = jt * 64 + nf * 16 + cl;
#pragma unroll
        for (int r = 0; r < 4; ++r)
          s[mf][nf][r] += bf2f(bias_w[(size_t)(mf * 16 + g * 4 + r) * 1024 + jc]);
      }
#pragma unroll
      for (int r = 0; r < 4; ++r){
        float mx = fmaxf(fmaxf(s[mf][0][r], s[mf][1][r]), fmaxf(s[mf][2][r], s[mf][3][r]));
        mx = fmaxf(mx, __shfl_xor(mx, 1));
        mx = fmaxf(mx, __shfl_xor(mx, 2));
        mx = fmaxf(mx, __shfl_xor(mx, 4));
        mx = fmaxf(mx, __shfl_xor(mx, 8));
        float mn = fmaxf(m_run[mf][r], mx);
        float fs = __expf(m_run[mf][r] - mn);
        m_run[mf][r] = mn;
        float rs = 0.f;
#pragma unroll
        for (int nf = 0; nf < 4; ++nf){
          float p = __expf(s[mf][nf][r] - mn);
          s[mf][nf][r] = p;
          rs += p;
        }
        rs += __shfl_xor(rs, 1);
        rs += __shfl_xor(rs, 2);
        rs += __shfl_xor(rs, 4);
        rs += __shfl_xor(rs, 8);
        l_run[mf][r] = l_run[mf][r] * fs + rs;
#pragma unroll
        for (int nd = 0; nd < 4; ++nd) o[mf][nd][r] *= fs;
      }
      // write P hi/lo to LDS (own wave's rows only)
#pragma unroll
      for (int nf = 0; nf < 4; ++nf)
#pragma unroll
        for (int r = 0; r < 4; ++r){
          u16 phi, plo; split2(s[mf][nf][r], phi, plo);
          int off = (w * 32 + mf * 16 + g * 4 + r) * 128 + (nf * 16 + cl) * 2;
          *(u16*)((char*)Ps0 + swz<7>(off)) = phi;
          *(u16*)((char*)Ps1 + swz<7>(off)) = plo;
        }
    }

    // -------- O += P V (3-term) --------
    bf16x8 pa[2][4];
#pragma unroll
    for (int mf = 0; mf < 2; ++mf){
      int row = (w * 32 + mf * 16 + cl) * 128;
      pa[mf][0] = *(const bf16x8*)((char*)Ps0 + swz<7>(row + (g * 8) * 2));
      pa[mf][1] = *(const bf16x8*)((char*)Ps0 + swz<7>(row + (32 + g * 8) * 2));
      pa[mf][2] = *(const bf16x8*)((char*)Ps1 + swz<7>(row + (g * 8) * 2));
      pa[mf][3] = *(const bf16x8*)((char*)Ps1 + swz<7>(row + (32 + g * 8) * 2));
    }
#pragma unroll
    for (int ks = 0; ks < 6; ++ks){
      int colb = ((ks & 1) * 32 + g * 8) * 2;
      const char* vb = (ks == 2 || ks == 3) ? (const char*)Vs1 : (const char*)Vs0;
      bf16x8 b4[4];
#pragma unroll
      for (int nd = 0; nd < 4; ++nd)
        b4[nd] = *(const bf16x8*)(vb + swz<7>((nd * 16 + cl) * 128 + colb));
#pragma unroll
      for (int mf = 0; mf < 2; ++mf)
#pragma unroll
        for (int nd = 0; nd < 4; ++nd)
          o[mf][nd] = __builtin_amdgcn_mfma_f32_16x16x32_bf16(pa[mf][AI[ks]], b4[nd], o[mf][nd], 0, 0, 0);
    }
  }

  // -------- normalize, stage O through LDS (reuse Ps), coalesced 16B stores --
  __syncthreads();
#pragma unroll
  for (int mf = 0; mf < 2; ++mf)
#pragma unroll
    for (int r = 0; r < 4; ++r){
      float inv = 1.f / l_run[mf][r];
      int row = w * 32 + mf * 16 + g * 4 + r;
#pragma unroll
      for (int nd = 0; nd < 4; ++nd){
        u16 hi, lo; split2(o[mf][nd][r] * inv, hi, lo);
        int off = row * 128 + (nd * 16 + cl) * 2;
        *(u16*)((char*)Ps0 + swz<7>(off)) = hi;
        *(u16*)((char*)Ps1 + swz<7>(off)) = lo;
      }
    }
  __syncthreads();
#pragma unroll
  for (int i = 0; i < 4; ++i){
    int s = tid + i * 256;
    int qr = s >> 3;                 // 0..127
    int seg = s & 7;                 // 8B-of-u16 segment
    int off = qr * 128 + seg * 16;
    size_t gb = ((size_t)b * 1024 + qt * 128 + qr) * 768 + h * 64 + seg * 8;
    *(float4*)(Ohi + gb) = *(const float4*)((char*)Ps0 + swz<7>(off));
    *(float4*)(Olo + gb) = *(const float4*)((char*)Ps1 + swz<7>(off));
  }
}

// ---------------------------------------------------------------------------
extern "C" void kernel_launch(void* const* d_in, const int* in_sizes, int n_in,
                              void* d_out, int out_size, void* d_ws, size_t ws_size,
                              hipStream_t stream)
{
  const float* x      = (const float*)d_in[0];
  const float* qkv_w  = (const float*)d_in[1];
  const float* q_bias = (const float*)d_in[2];
  const float* v_bias = (const float*)d_in[3];
  const float* table  = (const float*)d_in[4];
  const float* proj_w = (const float*)d_in[5];
  const float* proj_b = (const float*)d_in[6];
  const int*   relidx = (const int*)d_in[7];
  float* out = (float*)d_out;

  char* ws = (char*)d_ws;
  size_t off = 0;
  auto alloc = [&](size_t nelem) -> u16* {
    u16* p = (u16*)(ws + off);
    off += (nelem * 2 + 255) & ~(size_t)255;
    return p;
  };
  u16* Xhi  = alloc((size_t)8192 * 768);
  u16* Xlo  = alloc((size_t)8192 * 768);
  u16* Whi  = alloc((size_t)2304 * 768);
  u16* Wlo  = alloc((size_t)2304 * 768);
  u16* PWhi = alloc((size_t)768 * 768);
  u16* PWlo = alloc((size_t)768 * 768);
  u16* QKhi = alloc((size_t)8192 * 1536);
  u16* QKlo = alloc((size_t)8192 * 1536);
  u16* Vthi = alloc((size_t)8 * 12 * 64 * 1024);
  u16* Vtlo = alloc((size_t)8 * 12 * 64 * 1024);
  u16* Bias = alloc((size_t)12 * 1024 * 1024);
  // O reuses X space (X consumed by QKV GEMM before attention writes O)
  u16* Ohi = Xhi;
  u16* Olo = Xlo;

  k_split<<<6144, 256, 0, stream>>>(x, Xhi, Xlo);
  k_split<<<1728, 256, 0, stream>>>(qkv_w, Whi, Wlo);
  k_split<<<576,  256, 0, stream>>>(proj_w, PWhi, PWlo);
  k_bias<<<1024, 256, 0, stream>>>(relidx, table, Bias);

  k_gemm<0><<<dim3(18, 64), 256, 0, stream>>>(
      Xhi, Xhi, Xlo, Whi, Wlo, Whi,
      q_bias, v_bias, nullptr,
      QKhi, QKlo, Vthi, Vtlo, nullptr);

  k_attn<<<dim3(8, 8, 12), 256, 0, stream>>>(
      QKhi, QKlo, Vthi, Vtlo, Bias, Ohi, Olo);

  k_gemm<1><<<dim3(6, 64), 256, 0, stream>>>(
      Ohi, Ohi, Olo, PWhi, PWlo, PWhi,
      nullptr, nullptr, proj_b,
      nullptr, nullptr, nullptr, nullptr, out);
}

// Round 5
// 1244.947 us; speedup vs baseline: 1.7031x; 1.7031x over previous
//
#include <hip/hip_runtime.h>
#include <stdint.h>

using u16 = unsigned short;
using u32 = unsigned int;

typedef __bf16 bf16x8 __attribute__((ext_vector_type(8)));
typedef float f32x4 __attribute__((ext_vector_type(4)));

__device__ __forceinline__ u16 f2bf(float f){
  u32 u = __float_as_uint(f);
  return (u16)((u + 0x7FFFu + ((u >> 16) & 1u)) >> 16);
}
__device__ __forceinline__ float bf2f(u16 h){
  return __uint_as_float(((u32)h) << 16);
}
__device__ __forceinline__ void split2(float x, u16& hi, u16& lo){
  hi = f2bf(x);
  lo = f2bf(x - bf2f(hi));
}
template<int SH>
__device__ __forceinline__ int swz(int off){ return off ^ (((off >> SH) & 7) << 4); }

// ---------------- fp32 -> (hi,lo) bf16 split, one float4 per thread ----------
__global__ __launch_bounds__(256) void k_split(const float* __restrict__ src,
                                               u16* __restrict__ hi,
                                               u16* __restrict__ lo)
{
  int i = blockIdx.x * 256 + threadIdx.x;
  float4 v = ((const float4*)src)[i];
  ushort4 h, l;
  split2(v.x, h.x, l.x);
  split2(v.y, h.y, l.y);
  split2(v.z, h.z, l.z);
  split2(v.w, h.w, l.w);
  ((ushort4*)hi)[i] = h;
  ((ushort4*)lo)[i] = l;
}

// ---------------- bias precompute: bias[h][q][j] = bf16(table[relidx[q][j]][h])
__global__ __launch_bounds__(256) void k_bias(const int* __restrict__ relidx,
                                              const float* __restrict__ table,
                                              u16* __restrict__ bias)
{
  int q = blockIdx.x;
  int j0 = threadIdx.x * 4;
  int4 idx = *(const int4*)(relidx + q * 1024 + j0);
#pragma unroll
  for (int h = 0; h < 12; ++h){
    ushort4 o;
    o.x = f2bf(table[(size_t)idx.x * 12 + h]);
    o.y = f2bf(table[(size_t)idx.y * 12 + h]);
    o.z = f2bf(table[(size_t)idx.z * 12 + h]);
    o.w = f2bf(table[(size_t)idx.w * 12 + h]);
    *(ushort4*)(bias + ((size_t)h << 20) + q * 1024 + j0) = o;
  }
}

// ---------------- 128x128 tile GEMM, K' = 3*768 (split-bf16 3-term) ----------
// EPI 0: QKV. Q/K -> flat [8192][1536] row-major (dense stores);
//        V -> V^T (b,h,d,n) via LDS transpose (dense 256B runs).
// EPI 1: proj (bias, fp32 row-major out).
// NOTE: epilogue c-loops are #pragma unroll so ALL acc[][] indices are
// compile-time constants (rule #20: runtime-indexed ext_vector arrays
// force acc into scratch for the whole kernel -> 6.4 GB HBM scratch traffic).
template<int EPI>
__global__ __launch_bounds__(256) void k_gemm(
    const u16* __restrict__ A0, const u16* __restrict__ A1, const u16* __restrict__ A2,
    const u16* __restrict__ B0, const u16* __restrict__ B1, const u16* __restrict__ B2,
    const float* __restrict__ bq, const float* __restrict__ bv, const float* __restrict__ pb,
    u16* __restrict__ QKhi, u16* __restrict__ QKlo,
    u16* __restrict__ Vthi, u16* __restrict__ Vtlo,
    float* __restrict__ Cout)
{
  __shared__ u16 As[128 * 32];
  __shared__ u16 Bs[128 * 32];
  const int tid = threadIdx.x;
  const int lane = tid & 63;
  const int wid = tid >> 6;
  const int wr = wid >> 1, wc = wid & 1;
  const int g = lane >> 4, cl = lane & 15;
  const int bm = blockIdx.y << 7, bn = blockIdx.x << 7;
  const int rowA = tid >> 2, csA = tid & 3;

  f32x4 acc[4][4];
  f32x4 z4 = {0.f, 0.f, 0.f, 0.f};
#pragma unroll
  for (int i = 0; i < 4; ++i)
#pragma unroll
    for (int j = 0; j < 4; ++j) acc[i][j] = z4;

  float4 ra[2], rb[2];
  auto ldt = [&](int t, float4* xa, float4* xb){
    int ph = t / 24;
    int kin = (t - ph * 24) * 32;
    const u16* Ap = ph == 0 ? A0 : (ph == 1 ? A1 : A2);
    const u16* Bp = ph == 0 ? B0 : (ph == 1 ? B1 : B2);
#pragma unroll
    for (int i = 0; i < 2; ++i){
      xa[i] = *(const float4*)(Ap + (size_t)(bm + rowA + i * 64) * 768 + kin + csA * 8);
      xb[i] = *(const float4*)(Bp + (size_t)(bn + rowA + i * 64) * 768 + kin + csA * 8);
    }
  };
  ldt(0, ra, rb);

  for (int t = 0; t < 72; ++t){
    __syncthreads();
#pragma unroll
    for (int i = 0; i < 2; ++i){
      int s16 = (tid + i * 256) * 16;
      *(float4*)((char*)As + swz<6>(s16)) = ra[i];
      *(float4*)((char*)Bs + swz<6>(s16)) = rb[i];
    }
    __syncthreads();
    if (t + 1 < 72) ldt(t + 1, ra, rb);
    bf16x8 af[4], bfv[4];
#pragma unroll
    for (int mf = 0; mf < 4; ++mf)
      af[mf] = *(const bf16x8*)((char*)As + swz<6>(((wr * 64 + mf * 16 + cl) * 32 + g * 8) * 2));
#pragma unroll
    for (int nf = 0; nf < 4; ++nf)
      bfv[nf] = *(const bf16x8*)((char*)Bs + swz<6>(((wc * 64 + nf * 16 + cl) * 32 + g * 8) * 2));
#pragma unroll
    for (int mf = 0; mf < 4; ++mf)
#pragma unroll
      for (int nf = 0; nf < 4; ++nf)
        acc[mf][nf] = __builtin_amdgcn_mfma_f32_16x16x32_bf16(af[mf], bfv[nf], acc[mf][nf], 0, 0, 0);
  }

  if (EPI == 0){
    const int bb = bm >> 10;          // batch (tile never crosses: 1024 % 128 == 0)
    const int tokb = bm & 1023;
    if (blockIdx.x >= 12){
      // ---- V columns: transpose through LDS, coalesced 16B stores of V^T ----
      const int ccolbase = bn - 1536;
      u16* ShiT = As;                 // [32 cols][128 m] u16, swz<8> on byte offsets
      u16* SloT = Bs;
#pragma unroll
      for (int c = 0; c < 4; ++c){
        __syncthreads();
        if (wc == (c >> 1)){
#pragma unroll
          for (int nf2 = 0; nf2 < 2; ++nf2){
            const int nf = (c & 1) * 2 + nf2;     // compile-time constant
            int cc = nf2 * 16 + cl;               // 0..31 within chunk
            float bvv = bv[ccolbase + c * 32 + cc];
#pragma unroll
            for (int mf = 0; mf < 4; ++mf){
              ushort4 h4, l4;
              u16 hh_, ll_;
              split2(acc[mf][nf][0] + bvv, hh_, ll_); h4.x = hh_; l4.x = ll_;
              split2(acc[mf][nf][1] + bvv, hh_, ll_); h4.y = hh_; l4.y = ll_;
              split2(acc[mf][nf][2] + bvv, hh_, ll_); h4.z = hh_; l4.z = ll_;
              split2(acc[mf][nf][3] + bvv, hh_, ll_); h4.w = hh_; l4.w = ll_;
              int m0 = wr * 64 + mf * 16 + g * 4;
              int off = cc * 256 + m0 * 2;        // 8B-aligned
              *(ushort4*)((char*)ShiT + swz<8>(off)) = h4;
              *(ushort4*)((char*)SloT + swz<8>(off)) = l4;
            }
          }
        }
        __syncthreads();
#pragma unroll
        for (int i = 0; i < 2; ++i){
          int s = tid + i * 256;
          int dr = s >> 4;                        // 0..31
          int ms = (s & 15) * 8;                  // m start
          int off = dr * 256 + ms * 2;
          int ccol = ccolbase + c * 32 + dr;
          int hh = ccol >> 6, d = ccol & 63;
          size_t gb = ((size_t)(bb * 12 + hh) * 64 + d) * 1024 + tokb + ms;
          *(float4*)(Vthi + gb) = *(const float4*)((char*)ShiT + swz<8>(off));
          *(float4*)(Vtlo + gb) = *(const float4*)((char*)SloT + swz<8>(off));
        }
      }
    } else {
      // ---- Q/K: flat [8192][1536], bias+scale for Q, LDS-staged dense stores
      const bool isQ = (blockIdx.x < 6);
#pragma unroll
      for (int c = 0; c < 4; ++c){
        __syncthreads();
        if (wr == (c >> 1)){
#pragma unroll
          for (int mi = 0; mi < 2; ++mi){
            const int mf = (c & 1) * 2 + mi;      // compile-time constant
#pragma unroll
            for (int nf = 0; nf < 4; ++nf){
              int col = wc * 64 + nf * 16 + cl;   // 0..127 local
              float bqv = isQ ? bq[bn + col] : 0.f;
#pragma unroll
              for (int r = 0; r < 4; ++r){
                float v = acc[mf][nf][r];
                if (isQ) v = (v + bqv) * 0.125f;
                u16 hi, lo; split2(v, hi, lo);
                int off = ((mi * 16 + g * 4 + r) * 128 + col) * 2;
                *(u16*)((char*)As + swz<6>(off)) = hi;
                *(u16*)((char*)Bs + swz<6>(off)) = lo;
              }
            }
          }
        }
        __syncthreads();
#pragma unroll
        for (int i = 0; i < 2; ++i){
          int s = tid + i * 256;
          int rr = s >> 4;                        // 0..31
          int seg = s & 15;                       // 16B segment across 128 cols
          int off = rr * 256 + seg * 16;
          size_t gb = (size_t)(bm + c * 32 + rr) * 1536 + bn + seg * 8;
          *(float4*)(QKhi + gb) = *(const float4*)((char*)As + swz<6>(off));
          *(float4*)(QKlo + gb) = *(const float4*)((char*)Bs + swz<6>(off));
        }
      }
    }
    return;
  }

  // EPI == 1: proj epilogue, coalesced fp32 stores
#pragma unroll
  for (int mf = 0; mf < 4; ++mf)
#pragma unroll
    for (int nf = 0; nf < 4; ++nf)
#pragma unroll
      for (int r = 0; r < 4; ++r){
        int m = bm + wr * 64 + mf * 16 + g * 4 + r;
        int n = bn + wc * 64 + nf * 16 + cl;
        Cout[(size_t)m * 768 + n] = acc[mf][nf][r] + pb[n];
      }
}

// ---------------- flash attention, split-bf16, precomputed bias --------------
// Q/K from flat [8192][1536] (Q col h*64, K col 768+h*64); V^T (b,h,d,n).
__global__ __launch_bounds__(256) void k_attn(
    const u16* __restrict__ QKhi, const u16* __restrict__ QKlo,
    const u16* __restrict__ Vthi, const u16* __restrict__ Vtlo,
    const u16* __restrict__ bias,
    u16* __restrict__ Ohi, u16* __restrict__ Olo)
{
  __shared__ u16 Ks[64 * 128];   // [j][d_hi | d_lo]   16 KB  (swz<8>)
  __shared__ u16 Vs0[64 * 64];   // [d][j] hi           8 KB  (swz<7>)
  __shared__ u16 Vs1[64 * 64];   // [d][j] lo           8 KB
  __shared__ u16 Ps0[128 * 64];  // [q][j] P hi        16 KB  (swz<7>)
  __shared__ u16 Ps1[128 * 64];  // [q][j] P lo        16 KB

  const int tid = threadIdx.x;
  const int lane = tid & 63;
  const int w = tid >> 6;
  const int g = lane >> 4, cl = lane & 15;
  const int qt = blockIdx.x;
  const int b  = blockIdx.y;
  const int h  = blockIdx.z;
  const size_t rowbase = (size_t)b * 1024;             // token row base
  const size_t bhv = (size_t)(b * 12 + h) * (1024 * 64);
  const u16* bias_w = bias + ((size_t)h << 20) + (size_t)(qt * 128 + w * 32) * 1024;

  // Q fragments live in registers for the whole kernel (A' = [Qhi|Qhi|Qlo])
  bf16x8 aq[2][4];
#pragma unroll
  for (int mf = 0; mf < 2; ++mf){
    const u16* qh = QKhi + (rowbase + qt * 128 + w * 32 + mf * 16 + cl) * 1536 + h * 64;
    const u16* ql = QKlo + (rowbase + qt * 128 + w * 32 + mf * 16 + cl) * 1536 + h * 64;
    aq[mf][0] = *(const bf16x8*)(qh + g * 8);
    aq[mf][1] = *(const bf16x8*)(qh + 32 + g * 8);
    aq[mf][2] = *(const bf16x8*)(ql + g * 8);
    aq[mf][3] = *(const bf16x8*)(ql + 32 + g * 8);
  }

  f32x4 o[2][4];
  float m_run[2][4], l_run[2][4];
  f32x4 z4 = {0.f, 0.f, 0.f, 0.f};
#pragma unroll
  for (int mf = 0; mf < 2; ++mf){
#pragma unroll
    for (int nd = 0; nd < 4; ++nd) o[mf][nd] = z4;
#pragma unroll
    for (int r = 0; r < 4; ++r){ m_run[mf][r] = -1e30f; l_run[mf][r] = 0.f; }
  }

  float4 kv[8];
  auto ldkv = [&](int jt){
#pragma unroll
    for (int i = 0; i < 2; ++i){
      int s = tid + i * 256;
      int row = s >> 3, cs = s & 7;
      size_t kr = (rowbase + jt * 64 + row) * 1536 + 768 + h * 64 + cs * 8;
      kv[i]     = *(const float4*)(QKhi + kr);
      kv[2 + i] = *(const float4*)(QKlo + kr);
      kv[4 + i] = *(const float4*)(Vthi + bhv + (size_t)row * 1024 + jt * 64 + cs * 8);
      kv[6 + i] = *(const float4*)(Vtlo + bhv + (size_t)row * 1024 + jt * 64 + cs * 8);
    }
  };
  ldkv(0);

  const int AI[6] = {0, 1, 0, 1, 2, 3};
  const int BI[6] = {0, 1, 2, 3, 0, 1};

  for (int jt = 0; jt < 16; ++jt){
    __syncthreads();
#pragma unroll
    for (int i = 0; i < 2; ++i){
      int s = tid + i * 256;
      int row = s >> 3, cs = s & 7;
      *(float4*)((char*)Ks  + swz<8>(row * 256 + cs * 16))       = kv[i];
      *(float4*)((char*)Ks  + swz<8>(row * 256 + 128 + cs * 16)) = kv[2 + i];
      *(float4*)((char*)Vs0 + swz<7>(row * 128 + cs * 16))       = kv[4 + i];
      *(float4*)((char*)Vs1 + swz<7>(row * 128 + cs * 16))       = kv[6 + i];
    }
    __syncthreads();
    if (jt < 15) ldkv(jt + 1);

    // -------- S = Q K^T (3-term) --------
    f32x4 s[2][4];
#pragma unroll
    for (int mf = 0; mf < 2; ++mf)
#pragma unroll
      for (int nf = 0; nf < 4; ++nf) s[mf][nf] = z4;
#pragma unroll
    for (int ks = 0; ks < 6; ++ks){
      int t = BI[ks];
      int colb = ((t >> 1) * 64 + (t & 1) * 32 + g * 8) * 2;
      bf16x8 b4[4];
#pragma unroll
      for (int nf = 0; nf < 4; ++nf)
        b4[nf] = *(const bf16x8*)((char*)Ks + swz<8>((nf * 16 + cl) * 256 + colb));
#pragma unroll
      for (int mf = 0; mf < 2; ++mf)
#pragma unroll
        for (int nf = 0; nf < 4; ++nf)
          s[mf][nf] = __builtin_amdgcn_mfma_f32_16x16x32_bf16(aq[mf][AI[ks]], b4[nf], s[mf][nf], 0, 0, 0);
    }

    // -------- precomputed bias + online softmax --------
#pragma unroll
    for (int mf = 0; mf < 2; ++mf){
#pragma unroll
      for (int nf = 0; nf < 4; ++nf){
        int jc = jt * 64 + nf * 16 + cl;
#pragma unroll
        for (int r = 0; r < 4; ++r)
          s[mf][nf][r] += bf2f(bias_w[(size_t)(mf * 16 + g * 4 + r) * 1024 + jc]);
      }
#pragma unroll
      for (int r = 0; r < 4; ++r){
        float mx = fmaxf(fmaxf(s[mf][0][r], s[mf][1][r]), fmaxf(s[mf][2][r], s[mf][3][r]));
        mx = fmaxf(mx, __shfl_xor(mx, 1));
        mx = fmaxf(mx, __shfl_xor(mx, 2));
        mx = fmaxf(mx, __shfl_xor(mx, 4));
        mx = fmaxf(mx, __shfl_xor(mx, 8));
        float mn = fmaxf(m_run[mf][r], mx);
        float fs = __expf(m_run[mf][r] - mn);
        m_run[mf][r] = mn;
        float rs = 0.f;
#pragma unroll
        for (int nf = 0; nf < 4; ++nf){
          float p = __expf(s[mf][nf][r] - mn);
          s[mf][nf][r] = p;
          rs += p;
        }
        rs += __shfl_xor(rs, 1);
        rs += __shfl_xor(rs, 2);
        rs += __shfl_xor(rs, 4);
        rs += __shfl_xor(rs, 8);
        l_run[mf][r] = l_run[mf][r] * fs + rs;
#pragma unroll
        for (int nd = 0; nd < 4; ++nd) o[mf][nd][r] *= fs;
      }
      // write P hi/lo to LDS (own wave's rows only)
#pragma unroll
      for (int nf = 0; nf < 4; ++nf)
#pragma unroll
        for (int r = 0; r < 4; ++r){
          u16 phi, plo; split2(s[mf][nf][r], phi, plo);
          int off = (w * 32 + mf * 16 + g * 4 + r) * 128 + (nf * 16 + cl) * 2;
          *(u16*)((char*)Ps0 + swz<7>(off)) = phi;
          *(u16*)((char*)Ps1 + swz<7>(off)) = plo;
        }
    }

    // -------- O += P V (3-term) --------
    bf16x8 pa[2][4];
#pragma unroll
    for (int mf = 0; mf < 2; ++mf){
      int row = (w * 32 + mf * 16 + cl) * 128;
      pa[mf][0] = *(const bf16x8*)((char*)Ps0 + swz<7>(row + (g * 8) * 2));
      pa[mf][1] = *(const bf16x8*)((char*)Ps0 + swz<7>(row + (32 + g * 8) * 2));
      pa[mf][2] = *(const bf16x8*)((char*)Ps1 + swz<7>(row + (g * 8) * 2));
      pa[mf][3] = *(const bf16x8*)((char*)Ps1 + swz<7>(row + (32 + g * 8) * 2));
    }
#pragma unroll
    for (int ks = 0; ks < 6; ++ks){
      int colb = ((ks & 1) * 32 + g * 8) * 2;
      const char* vb = (ks == 2 || ks == 3) ? (const char*)Vs1 : (const char*)Vs0;
      bf16x8 b4[4];
#pragma unroll
      for (int nd = 0; nd < 4; ++nd)
        b4[nd] = *(const bf16x8*)(vb + swz<7>((nd * 16 + cl) * 128 + colb));
#pragma unroll
      for (int mf = 0; mf < 2; ++mf)
#pragma unroll
        for (int nd = 0; nd < 4; ++nd)
          o[mf][nd] = __builtin_amdgcn_mfma_f32_16x16x32_bf16(pa[mf][AI[ks]], b4[nd], o[mf][nd], 0, 0, 0);
    }
  }

  // -------- normalize, stage O through LDS (reuse Ps), coalesced 16B stores --
  __syncthreads();
#pragma unroll
  for (int mf = 0; mf < 2; ++mf)
#pragma unroll
    for (int r = 0; r < 4; ++r){
      float inv = 1.f / l_run[mf][r];
      int row = w * 32 + mf * 16 + g * 4 + r;
#pragma unroll
      for (int nd = 0; nd < 4; ++nd){
        u16 hi, lo; split2(o[mf][nd][r] * inv, hi, lo);
        int off = row * 128 + (nd * 16 + cl) * 2;
        *(u16*)((char*)Ps0 + swz<7>(off)) = hi;
        *(u16*)((char*)Ps1 + swz<7>(off)) = lo;
      }
    }
  __syncthreads();
#pragma unroll
  for (int i = 0; i < 4; ++i){
    int s = tid + i * 256;
    int qr = s >> 3;                 // 0..127
    int seg = s & 7;                 // 8B-of-u16 segment
    int off = qr * 128 + seg * 16;
    size_t gb = ((size_t)b * 1024 + qt * 128 + qr) * 768 + h * 64 + seg * 8;
    *(float4*)(Ohi + gb) = *(const float4*)((char*)Ps0 + swz<7>(off));
    *(float4*)(Olo + gb) = *(const float4*)((char*)Ps1 + swz<7>(off));
  }
}

// ---------------------------------------------------------------------------
extern "C" void kernel_launch(void* const* d_in, const int* in_sizes, int n_in,
                              void* d_out, int out_size, void* d_ws, size_t ws_size,
                              hipStream_t stream)
{
  const float* x      = (const float*)d_in[0];
  const float* qkv_w  = (const float*)d_in[1];
  const float* q_bias = (const float*)d_in[2];
  const float* v_bias = (const float*)d_in[3];
  const float* table  = (const float*)d_in[4];
  const float* proj_w = (const float*)d_in[5];
  const float* proj_b = (const float*)d_in[6];
  const int*   relidx = (const int*)d_in[7];
  float* out = (float*)d_out;

  char* ws = (char*)d_ws;
  size_t off = 0;
  auto alloc = [&](size_t nelem) -> u16* {
    u16* p = (u16*)(ws + off);
    off += (nelem * 2 + 255) & ~(size_t)255;
    return p;
  };
  u16* Xhi  = alloc((size_t)8192 * 768);
  u16* Xlo  = alloc((size_t)8192 * 768);
  u16* Whi  = alloc((size_t)2304 * 768);
  u16* Wlo  = alloc((size_t)2304 * 768);
  u16* PWhi = alloc((size_t)768 * 768);
  u16* PWlo = alloc((size_t)768 * 768);
  u16* QKhi = alloc((size_t)8192 * 1536);
  u16* QKlo = alloc((size_t)8192 * 1536);
  u16* Vthi = alloc((size_t)8 * 12 * 64 * 1024);
  u16* Vtlo = alloc((size_t)8 * 12 * 64 * 1024);
  u16* Bias = alloc((size_t)12 * 1024 * 1024);
  // O reuses X space (X consumed by QKV GEMM before attention writes O)
  u16* Ohi = Xhi;
  u16* Olo = Xlo;

  k_split<<<6144, 256, 0, stream>>>(x, Xhi, Xlo);
  k_split<<<1728, 256, 0, stream>>>(qkv_w, Whi, Wlo);
  k_split<<<576,  256, 0, stream>>>(proj_w, PWhi, PWlo);
  k_bias<<<1024, 256, 0, stream>>>(relidx, table, Bias);

  k_gemm<0><<<dim3(18, 64), 256, 0, stream>>>(
      Xhi, Xhi, Xlo, Whi, Wlo, Whi,
      q_bias, v_bias, nullptr,
      QKhi, QKlo, Vthi, Vtlo, nullptr);

  k_attn<<<dim3(8, 8, 12), 256, 0, stream>>>(
      QKhi, QKlo, Vthi, Vtlo, Bias, Ohi, Olo);

  k_gemm<1><<<dim3(6, 64), 256, 0, stream>>>(
      Ohi, Ohi, Olo, PWhi, PWlo, PWhi,
      nullptr, nullptr, proj_b,
      nullptr, nullptr, nullptr, nullptr, out);
}

// Round 6
// 765.097 us; speedup vs baseline: 2.7713x; 1.6272x over previous
//
#include <hip/hip_runtime.h>
#include <stdint.h>

using u16 = unsigned short;
using u32 = unsigned int;

typedef __bf16 bf16x8 __attribute__((ext_vector_type(8)));
typedef float f32x4 __attribute__((ext_vector_type(4)));

__device__ __forceinline__ u16 f2bf(float f){
  u32 u = __float_as_uint(f);
  return (u16)((u + 0x7FFFu + ((u >> 16) & 1u)) >> 16);
}
__device__ __forceinline__ float bf2f(u16 h){
  return __uint_as_float(((u32)h) << 16);
}
__device__ __forceinline__ void split2(float x, u16& hi, u16& lo){
  hi = f2bf(x);
  lo = f2bf(x - bf2f(hi));
}
template<int SH>
__device__ __forceinline__ int swz(int off){ return off ^ (((off >> SH) & 7) << 4); }

// ---------------- fp32 -> (hi,lo) bf16 split, one float4 per thread ----------
__global__ __launch_bounds__(256) void k_split(const float* __restrict__ src,
                                               u16* __restrict__ hi,
                                               u16* __restrict__ lo)
{
  int i = blockIdx.x * 256 + threadIdx.x;
  float4 v = ((const float4*)src)[i];
  ushort4 h, l;
  split2(v.x, h.x, l.x);
  split2(v.y, h.y, l.y);
  split2(v.z, h.z, l.z);
  split2(v.w, h.w, l.w);
  ((ushort4*)hi)[i] = h;
  ((ushort4*)lo)[i] = l;
}

// ---------------- bias precompute: bias[h][q][j] = bf16(table[relidx[q][j]][h])
__global__ __launch_bounds__(256) void k_bias(const int* __restrict__ relidx,
                                              const float* __restrict__ table,
                                              u16* __restrict__ bias)
{
  int q = blockIdx.x;
  int j0 = threadIdx.x * 4;
  int4 idx = *(const int4*)(relidx + q * 1024 + j0);
#pragma unroll
  for (int h = 0; h < 12; ++h){
    ushort4 o;
    o.x = f2bf(table[(size_t)idx.x * 12 + h]);
    o.y = f2bf(table[(size_t)idx.y * 12 + h]);
    o.z = f2bf(table[(size_t)idx.z * 12 + h]);
    o.w = f2bf(table[(size_t)idx.w * 12 + h]);
    *(ushort4*)(bias + ((size_t)h << 20) + q * 1024 + j0) = o;
  }
}

// ---------------- 128x128 tile GEMM, K' = 3*768 (split-bf16 3-term) ----------
// Staging registers are NAMED struct members returned BY VALUE (rule #20 /
// SROA: pointer-arg arrays land in scratch -> ~1.1 GB HBM write traffic).
struct Stage { float4 a0, a1, b0, b1; };

template<int EPI>
__global__ __launch_bounds__(256) void k_gemm(
    const u16* __restrict__ A0, const u16* __restrict__ A1, const u16* __restrict__ A2,
    const u16* __restrict__ B0, const u16* __restrict__ B1, const u16* __restrict__ B2,
    const float* __restrict__ bq, const float* __restrict__ bv, const float* __restrict__ pb,
    u16* __restrict__ QKhi, u16* __restrict__ QKlo,
    u16* __restrict__ Vthi, u16* __restrict__ Vtlo,
    float* __restrict__ Cout)
{
  __shared__ u16 As[128 * 32];
  __shared__ u16 Bs[128 * 32];
  const int tid = threadIdx.x;
  const int lane = tid & 63;
  const int wid = tid >> 6;
  const int wr = wid >> 1, wc = wid & 1;
  const int g = lane >> 4, cl = lane & 15;
  const int bm = blockIdx.y << 7, bn = blockIdx.x << 7;
  const int rowA = tid >> 2, csA = tid & 3;

  f32x4 acc[4][4];
  f32x4 z4 = {0.f, 0.f, 0.f, 0.f};
#pragma unroll
  for (int i = 0; i < 4; ++i)
#pragma unroll
    for (int j = 0; j < 4; ++j) acc[i][j] = z4;

  auto ldt = [&](int t) -> Stage {
    int ph = t / 24;
    int kin = (t - ph * 24) * 32;
    const u16* Ap = ph == 0 ? A0 : (ph == 1 ? A1 : A2);
    const u16* Bp = ph == 0 ? B0 : (ph == 1 ? B1 : B2);
    Stage s;
    s.a0 = *(const float4*)(Ap + (size_t)(bm + rowA) * 768 + kin + csA * 8);
    s.a1 = *(const float4*)(Ap + (size_t)(bm + rowA + 64) * 768 + kin + csA * 8);
    s.b0 = *(const float4*)(Bp + (size_t)(bn + rowA) * 768 + kin + csA * 8);
    s.b1 = *(const float4*)(Bp + (size_t)(bn + rowA + 64) * 768 + kin + csA * 8);
    return s;
  };
  Stage cur = ldt(0);

  for (int t = 0; t < 72; ++t){
    __syncthreads();
    {
      int s0 = tid * 16;
      int s1 = (tid + 256) * 16;
      *(float4*)((char*)As + swz<6>(s0)) = cur.a0;
      *(float4*)((char*)Bs + swz<6>(s0)) = cur.b0;
      *(float4*)((char*)As + swz<6>(s1)) = cur.a1;
      *(float4*)((char*)Bs + swz<6>(s1)) = cur.b1;
    }
    __syncthreads();
    Stage nxt;
    if (t + 1 < 72) nxt = ldt(t + 1);
    bf16x8 af[4], bfv[4];
#pragma unroll
    for (int mf = 0; mf < 4; ++mf)
      af[mf] = *(const bf16x8*)((char*)As + swz<6>(((wr * 64 + mf * 16 + cl) * 32 + g * 8) * 2));
#pragma unroll
    for (int nf = 0; nf < 4; ++nf)
      bfv[nf] = *(const bf16x8*)((char*)Bs + swz<6>(((wc * 64 + nf * 16 + cl) * 32 + g * 8) * 2));
#pragma unroll
    for (int mf = 0; mf < 4; ++mf)
#pragma unroll
      for (int nf = 0; nf < 4; ++nf)
        acc[mf][nf] = __builtin_amdgcn_mfma_f32_16x16x32_bf16(af[mf], bfv[nf], acc[mf][nf], 0, 0, 0);
    cur = nxt;
  }

  if (EPI == 0){
    const int bb = bm >> 10;          // batch (tile never crosses: 1024 % 128 == 0)
    const int tokb = bm & 1023;
    if (blockIdx.x >= 12){
      // ---- V columns: transpose through LDS, coalesced 16B stores of V^T ----
      const int ccolbase = bn - 1536;
      u16* ShiT = As;                 // [32 cols][128 m] u16, swz<8> on byte offsets
      u16* SloT = Bs;
#pragma unroll
      for (int c = 0; c < 4; ++c){
        __syncthreads();
        if (wc == (c >> 1)){
#pragma unroll
          for (int nf2 = 0; nf2 < 2; ++nf2){
            const int nf = (c & 1) * 2 + nf2;     // compile-time constant
            int cc = nf2 * 16 + cl;               // 0..31 within chunk
            float bvv = bv[ccolbase + c * 32 + cc];
#pragma unroll
            for (int mf = 0; mf < 4; ++mf){
              ushort4 h4, l4;
              u16 hh_, ll_;
              split2(acc[mf][nf][0] + bvv, hh_, ll_); h4.x = hh_; l4.x = ll_;
              split2(acc[mf][nf][1] + bvv, hh_, ll_); h4.y = hh_; l4.y = ll_;
              split2(acc[mf][nf][2] + bvv, hh_, ll_); h4.z = hh_; l4.z = ll_;
              split2(acc[mf][nf][3] + bvv, hh_, ll_); h4.w = hh_; l4.w = ll_;
              int m0 = wr * 64 + mf * 16 + g * 4;
              int off = cc * 256 + m0 * 2;        // 8B-aligned
              *(ushort4*)((char*)ShiT + swz<8>(off)) = h4;
              *(ushort4*)((char*)SloT + swz<8>(off)) = l4;
            }
          }
        }
        __syncthreads();
#pragma unroll
        for (int i = 0; i < 2; ++i){
          int s = tid + i * 256;
          int dr = s >> 4;                        // 0..31
          int ms = (s & 15) * 8;                  // m start
          int off = dr * 256 + ms * 2;
          int ccol = ccolbase + c * 32 + dr;
          int hh = ccol >> 6, d = ccol & 63;
          size_t gb = ((size_t)(bb * 12 + hh) * 64 + d) * 1024 + tokb + ms;
          *(float4*)(Vthi + gb) = *(const float4*)((char*)ShiT + swz<8>(off));
          *(float4*)(Vtlo + gb) = *(const float4*)((char*)SloT + swz<8>(off));
        }
      }
    } else {
      // ---- Q/K: flat [8192][1536], bias+scale for Q, LDS-staged dense stores
      const bool isQ = (blockIdx.x < 6);
#pragma unroll
      for (int c = 0; c < 4; ++c){
        __syncthreads();
        if (wr == (c >> 1)){
#pragma unroll
          for (int mi = 0; mi < 2; ++mi){
            const int mf = (c & 1) * 2 + mi;      // compile-time constant
#pragma unroll
            for (int nf = 0; nf < 4; ++nf){
              int col = wc * 64 + nf * 16 + cl;   // 0..127 local
              float bqv = isQ ? bq[bn + col] : 0.f;
#pragma unroll
              for (int r = 0; r < 4; ++r){
                float v = acc[mf][nf][r];
                if (isQ) v = (v + bqv) * 0.125f;
                u16 hi, lo; split2(v, hi, lo);
                int off = ((mi * 16 + g * 4 + r) * 128 + col) * 2;
                *(u16*)((char*)As + swz<6>(off)) = hi;
                *(u16*)((char*)Bs + swz<6>(off)) = lo;
              }
            }
          }
        }
        __syncthreads();
#pragma unroll
        for (int i = 0; i < 2; ++i){
          int s = tid + i * 256;
          int rr = s >> 4;                        // 0..31
          int seg = s & 15;                       // 16B segment across 128 cols
          int off = rr * 256 + seg * 16;
          size_t gb = (size_t)(bm + c * 32 + rr) * 1536 + bn + seg * 8;
          *(float4*)(QKhi + gb) = *(const float4*)((char*)As + swz<6>(off));
          *(float4*)(QKlo + gb) = *(const float4*)((char*)Bs + swz<6>(off));
        }
      }
    }
    return;
  }

  // EPI == 1: proj epilogue, coalesced fp32 stores
#pragma unroll
  for (int mf = 0; mf < 4; ++mf)
#pragma unroll
    for (int nf = 0; nf < 4; ++nf)
#pragma unroll
      for (int r = 0; r < 4; ++r){
        int m = bm + wr * 64 + mf * 16 + g * 4 + r;
        int n = bn + wc * 64 + nf * 16 + cl;
        Cout[(size_t)m * 768 + n] = acc[mf][nf][r] + pb[n];
      }
}

// ---------------- flash attention, split-bf16, precomputed bias --------------
// Q/K from flat [8192][1536] (Q col h*64, K col 768+h*64); V^T (b,h,d,n).
// K/V staging in NAMED struct members (no pointer-arg arrays -> no scratch).
struct KV { float4 kh0, kh1, kl0, kl1, vh0, vh1, vl0, vl1; };

__global__ __launch_bounds__(256) void k_attn(
    const u16* __restrict__ QKhi, const u16* __restrict__ QKlo,
    const u16* __restrict__ Vthi, const u16* __restrict__ Vtlo,
    const u16* __restrict__ bias,
    u16* __restrict__ Ohi, u16* __restrict__ Olo)
{
  __shared__ u16 Ks[64 * 128];   // [j][d_hi | d_lo]   16 KB  (swz<8>)
  __shared__ u16 Vs0[64 * 64];   // [d][j] hi           8 KB  (swz<7>)
  __shared__ u16 Vs1[64 * 64];   // [d][j] lo           8 KB
  __shared__ u16 Ps0[128 * 64];  // [q][j] P hi        16 KB  (swz<7>)
  __shared__ u16 Ps1[128 * 64];  // [q][j] P lo        16 KB

  const int tid = threadIdx.x;
  const int lane = tid & 63;
  const int w = tid >> 6;
  const int g = lane >> 4, cl = lane & 15;
  const int qt = blockIdx.x;
  const int b  = blockIdx.y;
  const int h  = blockIdx.z;
  const size_t rowbase = (size_t)b * 1024;             // token row base
  const size_t bhv = (size_t)(b * 12 + h) * (1024 * 64);
  const u16* bias_w = bias + ((size_t)h << 20) + (size_t)(qt * 128 + w * 32) * 1024;

  // Q fragments live in registers for the whole kernel (A' = [Qhi|Qhi|Qlo])
  bf16x8 aq[2][4];
#pragma unroll
  for (int mf = 0; mf < 2; ++mf){
    const u16* qh = QKhi + (rowbase + qt * 128 + w * 32 + mf * 16 + cl) * 1536 + h * 64;
    const u16* ql = QKlo + (rowbase + qt * 128 + w * 32 + mf * 16 + cl) * 1536 + h * 64;
    aq[mf][0] = *(const bf16x8*)(qh + g * 8);
    aq[mf][1] = *(const bf16x8*)(qh + 32 + g * 8);
    aq[mf][2] = *(const bf16x8*)(ql + g * 8);
    aq[mf][3] = *(const bf16x8*)(ql + 32 + g * 8);
  }

  f32x4 o[2][4];
  float m_run[2][4], l_run[2][4];
  f32x4 z4 = {0.f, 0.f, 0.f, 0.f};
#pragma unroll
  for (int mf = 0; mf < 2; ++mf){
#pragma unroll
    for (int nd = 0; nd < 4; ++nd) o[mf][nd] = z4;
#pragma unroll
    for (int r = 0; r < 4; ++r){ m_run[mf][r] = -1e30f; l_run[mf][r] = 0.f; }
  }

  const int row0 = tid >> 3,        cs0 = tid & 7;
  const int row1 = (tid + 256) >> 3, cs1 = tid & 7;   // (tid+256)&7 == tid&7
  auto ldkv = [&](int jt) -> KV {
    KV r;
    size_t kr0 = (rowbase + jt * 64 + row0) * 1536 + 768 + h * 64 + cs0 * 8;
    size_t kr1 = (rowbase + jt * 64 + row1) * 1536 + 768 + h * 64 + cs1 * 8;
    r.kh0 = *(const float4*)(QKhi + kr0);
    r.kh1 = *(const float4*)(QKhi + kr1);
    r.kl0 = *(const float4*)(QKlo + kr0);
    r.kl1 = *(const float4*)(QKlo + kr1);
    size_t vr0 = bhv + (size_t)row0 * 1024 + jt * 64 + cs0 * 8;
    size_t vr1 = bhv + (size_t)row1 * 1024 + jt * 64 + cs1 * 8;
    r.vh0 = *(const float4*)(Vthi + vr0);
    r.vh1 = *(const float4*)(Vthi + vr1);
    r.vl0 = *(const float4*)(Vtlo + vr0);
    r.vl1 = *(const float4*)(Vtlo + vr1);
    return r;
  };
  KV cur = ldkv(0);

  const int AI[6] = {0, 1, 0, 1, 2, 3};
  const int BI[6] = {0, 1, 2, 3, 0, 1};

  for (int jt = 0; jt < 16; ++jt){
    __syncthreads();
    {
      *(float4*)((char*)Ks  + swz<8>(row0 * 256 + cs0 * 16))       = cur.kh0;
      *(float4*)((char*)Ks  + swz<8>(row1 * 256 + cs1 * 16))       = cur.kh1;
      *(float4*)((char*)Ks  + swz<8>(row0 * 256 + 128 + cs0 * 16)) = cur.kl0;
      *(float4*)((char*)Ks  + swz<8>(row1 * 256 + 128 + cs1 * 16)) = cur.kl1;
      *(float4*)((char*)Vs0 + swz<7>(row0 * 128 + cs0 * 16))       = cur.vh0;
      *(float4*)((char*)Vs0 + swz<7>(row1 * 128 + cs1 * 16))       = cur.vh1;
      *(float4*)((char*)Vs1 + swz<7>(row0 * 128 + cs0 * 16))       = cur.vl0;
      *(float4*)((char*)Vs1 + swz<7>(row1 * 128 + cs1 * 16))       = cur.vl1;
    }
    __syncthreads();
    KV nxt;
    if (jt < 15) nxt = ldkv(jt + 1);

    // -------- S = Q K^T (3-term) --------
    f32x4 s[2][4];
#pragma unroll
    for (int mf = 0; mf < 2; ++mf)
#pragma unroll
      for (int nf = 0; nf < 4; ++nf) s[mf][nf] = z4;
#pragma unroll
    for (int ks = 0; ks < 6; ++ks){
      int t = BI[ks];
      int colb = ((t >> 1) * 64 + (t & 1) * 32 + g * 8) * 2;
      bf16x8 b4[4];
#pragma unroll
      for (int nf = 0; nf < 4; ++nf)
        b4[nf] = *(const bf16x8*)((char*)Ks + swz<8>((nf * 16 + cl) * 256 + colb));
#pragma unroll
      for (int mf = 0; mf < 2; ++mf)
#pragma unroll
        for (int nf = 0; nf < 4; ++nf)
          s[mf][nf] = __builtin_amdgcn_mfma_f32_16x16x32_bf16(aq[mf][AI[ks]], b4[nf], s[mf][nf], 0, 0, 0);
    }

    // -------- precomputed bias + online softmax --------
#pragma unroll
    for (int mf = 0; mf < 2; ++mf){
#pragma unroll
      for (int nf = 0; nf < 4; ++nf){
        int jc = jt * 64 + nf * 16 + cl;
#pragma unroll
        for (int r = 0; r < 4; ++r)
          s[mf][nf][r] += bf2f(bias_w[(size_t)(mf * 16 + g * 4 + r) * 1024 + jc]);
      }
#pragma unroll
      for (int r = 0; r < 4; ++r){
        float mx = fmaxf(fmaxf(s[mf][0][r], s[mf][1][r]), fmaxf(s[mf][2][r], s[mf][3][r]));
        mx = fmaxf(mx, __shfl_xor(mx, 1));
        mx = fmaxf(mx, __shfl_xor(mx, 2));
        mx = fmaxf(mx, __shfl_xor(mx, 4));
        mx = fmaxf(mx, __shfl_xor(mx, 8));
        float mn = fmaxf(m_run[mf][r], mx);
        float fs = __expf(m_run[mf][r] - mn);
        m_run[mf][r] = mn;
        float rs = 0.f;
#pragma unroll
        for (int nf = 0; nf < 4; ++nf){
          float p = __expf(s[mf][nf][r] - mn);
          s[mf][nf][r] = p;
          rs += p;
        }
        rs += __shfl_xor(rs, 1);
        rs += __shfl_xor(rs, 2);
        rs += __shfl_xor(rs, 4);
        rs += __shfl_xor(rs, 8);
        l_run[mf][r] = l_run[mf][r] * fs + rs;
#pragma unroll
        for (int nd = 0; nd < 4; ++nd) o[mf][nd][r] *= fs;
      }
      // write P hi/lo to LDS (own wave's rows only)
#pragma unroll
      for (int nf = 0; nf < 4; ++nf)
#pragma unroll
        for (int r = 0; r < 4; ++r){
          u16 phi, plo; split2(s[mf][nf][r], phi, plo);
          int off = (w * 32 + mf * 16 + g * 4 + r) * 128 + (nf * 16 + cl) * 2;
          *(u16*)((char*)Ps0 + swz<7>(off)) = phi;
          *(u16*)((char*)Ps1 + swz<7>(off)) = plo;
        }
    }

    // -------- O += P V (3-term) --------
    bf16x8 pa[2][4];
#pragma unroll
    for (int mf = 0; mf < 2; ++mf){
      int row = (w * 32 + mf * 16 + cl) * 128;
      pa[mf][0] = *(const bf16x8*)((char*)Ps0 + swz<7>(row + (g * 8) * 2));
      pa[mf][1] = *(const bf16x8*)((char*)Ps0 + swz<7>(row + (32 + g * 8) * 2));
      pa[mf][2] = *(const bf16x8*)((char*)Ps1 + swz<7>(row + (g * 8) * 2));
      pa[mf][3] = *(const bf16x8*)((char*)Ps1 + swz<7>(row + (32 + g * 8) * 2));
    }
#pragma unroll
    for (int ks = 0; ks < 6; ++ks){
      int colb = ((ks & 1) * 32 + g * 8) * 2;
      const char* vb = (ks == 2 || ks == 3) ? (const char*)Vs1 : (const char*)Vs0;
      bf16x8 b4[4];
#pragma unroll
      for (int nd = 0; nd < 4; ++nd)
        b4[nd] = *(const bf16x8*)(vb + swz<7>((nd * 16 + cl) * 128 + colb));
#pragma unroll
      for (int mf = 0; mf < 2; ++mf)
#pragma unroll
        for (int nd = 0; nd < 4; ++nd)
          o[mf][nd] = __builtin_amdgcn_mfma_f32_16x16x32_bf16(pa[mf][AI[ks]], b4[nd], o[mf][nd], 0, 0, 0);
    }
    cur = nxt;
  }

  // -------- normalize, stage O through LDS (reuse Ps), coalesced 16B stores --
  __syncthreads();
#pragma unroll
  for (int mf = 0; mf < 2; ++mf)
#pragma unroll
    for (int r = 0; r < 4; ++r){
      float inv = 1.f / l_run[mf][r];
      int row = w * 32 + mf * 16 + g * 4 + r;
#pragma unroll
      for (int nd = 0; nd < 4; ++nd){
        u16 hi, lo; split2(o[mf][nd][r] * inv, hi, lo);
        int off = row * 128 + (nd * 16 + cl) * 2;
        *(u16*)((char*)Ps0 + swz<7>(off)) = hi;
        *(u16*)((char*)Ps1 + swz<7>(off)) = lo;
      }
    }
  __syncthreads();
#pragma unroll
  for (int i = 0; i < 4; ++i){
    int s = tid + i * 256;
    int qr = s >> 3;                 // 0..127
    int seg = s & 7;                 // 8B-of-u16 segment
    int off = qr * 128 + seg * 16;
    size_t gb = ((size_t)b * 1024 + qt * 128 + qr) * 768 + h * 64 + seg * 8;
    *(float4*)(Ohi + gb) = *(const float4*)((char*)Ps0 + swz<7>(off));
    *(float4*)(Olo + gb) = *(const float4*)((char*)Ps1 + swz<7>(off));
  }
}

// ---------------------------------------------------------------------------
extern "C" void kernel_launch(void* const* d_in, const int* in_sizes, int n_in,
                              void* d_out, int out_size, void* d_ws, size_t ws_size,
                              hipStream_t stream)
{
  const float* x      = (const float*)d_in[0];
  const float* qkv_w  = (const float*)d_in[1];
  const float* q_bias = (const float*)d_in[2];
  const float* v_bias = (const float*)d_in[3];
  const float* table  = (const float*)d_in[4];
  const float* proj_w = (const float*)d_in[5];
  const float* proj_b = (const float*)d_in[6];
  const int*   relidx = (const int*)d_in[7];
  float* out = (float*)d_out;

  char* ws = (char*)d_ws;
  size_t off = 0;
  auto alloc = [&](size_t nelem) -> u16* {
    u16* p = (u16*)(ws + off);
    off += (nelem * 2 + 255) & ~(size_t)255;
    return p;
  };
  u16* Xhi  = alloc((size_t)8192 * 768);
  u16* Xlo  = alloc((size_t)8192 * 768);
  u16* Whi  = alloc((size_t)2304 * 768);
  u16* Wlo  = alloc((size_t)2304 * 768);
  u16* PWhi = alloc((size_t)768 * 768);
  u16* PWlo = alloc((size_t)768 * 768);
  u16* QKhi = alloc((size_t)8192 * 1536);
  u16* QKlo = alloc((size_t)8192 * 1536);
  u16* Vthi = alloc((size_t)8 * 12 * 64 * 1024);
  u16* Vtlo = alloc((size_t)8 * 12 * 64 * 1024);
  u16* Bias = alloc((size_t)12 * 1024 * 1024);
  // O reuses X space (X consumed by QKV GEMM before attention writes O)
  u16* Ohi = Xhi;
  u16* Olo = Xlo;

  k_split<<<6144, 256, 0, stream>>>(x, Xhi, Xlo);
  k_split<<<1728, 256, 0, stream>>>(qkv_w, Whi, Wlo);
  k_split<<<576,  256, 0, stream>>>(proj_w, PWhi, PWlo);
  k_bias<<<1024, 256, 0, stream>>>(relidx, table, Bias);

  k_gemm<0><<<dim3(18, 64), 256, 0, stream>>>(
      Xhi, Xhi, Xlo, Whi, Wlo, Whi,
      q_bias, v_bias, nullptr,
      QKhi, QKlo, Vthi, Vtlo, nullptr);

  k_attn<<<dim3(8, 8, 12), 256, 0, stream>>>(
      QKhi, QKlo, Vthi, Vtlo, Bias, Ohi, Olo);

  k_gemm<1><<<dim3(6, 64), 256, 0, stream>>>(
      Ohi, Ohi, Olo, PWhi, PWlo, PWhi,
      nullptr, nullptr, proj_b,
      nullptr, nullptr, nullptr, nullptr, out);
}